// Round 16
// baseline (628.571 us; speedup 1.0000x reference)
//
#include <hip/hip_runtime.h>
#include <hip/hip_bf16.h>

#define NPIX 16384          // 128*128
#define S_TOT 262144        // 128*128*16

typedef __attribute__((ext_vector_type(8))) short bf16x8;
typedef __attribute__((ext_vector_type(4))) float f32x4;

__device__ __forceinline__ float lrelu(float v) { return fmaxf(v, 0.2f * v); }
__device__ __forceinline__ unsigned short f2b(float f) {
  unsigned u = __float_as_uint(f);
  return (unsigned short)((u + 0x7FFFu + ((u >> 16) & 1u)) >> 16);   // RNE
}
// packed f32x2 -> bf16x2 (RNE) [software: HW cvt_pk asm NaN'd, R7]
__device__ __forceinline__ unsigned cvtpk(float a, float b) {
  return (unsigned)f2b(a) | ((unsigned)f2b(b) << 16);
}
__device__ __forceinline__ float b2f(short s) {
  return __uint_as_float(((unsigned)(unsigned short)s) << 16);
}
__device__ __forceinline__ float f_lo(int u) { return __uint_as_float((unsigned)u << 16); }
__device__ __forceinline__ float f_hi(int u) { return __uint_as_float((unsigned)u & 0xffff0000u); }

// ---- device-global scratch (write-before-read each call) ----
__device__ float g_alpha[5 * 256];
__device__ float g_biasall[1600];       // b1(256) | beta l0..4 (1280) | bc(64)
__device__ float g_amod[1024];          // zc = z@wz^T+bz ; a0|a1|a2|a3
__device__ float g_sigma[S_TOT];
__device__ short g_c[S_TOT * 64];       // bf16 [sample][64]
__device__ short g_featb[NPIX * 64];    // bf16 [px][64]
__device__ short g_y1[NPIX * 256];      // bf16 [px][256]
__device__ short g_y2[NPIX * 256];
__device__ short g_y3[NPIX * 256];
__device__ short g_t [NPIX * 256];
// MLP packed A-frags: L1 (K=160) 40960 | 5x ML (K=256) 65536 ea | wc 16384 | wsig 4096
__device__ short g_wpack[389120];
// CNN packed A-frags: c1(16384) | c2a,c2b,c3a,c3b (589824 ea) | c4a,c4b (65536 ea)
#define O_C1  0
#define O_C2A 16384
#define O_C2B (16384 + 589824)
#define O_C3A (16384 + 2 * 589824)
#define O_C3B (16384 + 3 * 589824)
#define O_C4A (16384 + 4 * 589824)
#define O_C4B (16384 + 4 * 589824 + 65536)
__device__ short g_wpack2[2506752];

// ---------------- kparams ----------------
__global__ __launch_bounds__(256) void kparams(const float* __restrict__ z,
    const float* __restrict__ wa, const float* __restrict__ ba,
    const float* __restrict__ wb, const float* __restrict__ bb,
    const float* __restrict__ wz, const float* __restrict__ bz,
    const float* __restrict__ b1, const float* __restrict__ bc) {
  __shared__ float zs[256];
  const int t = threadIdx.x;
  zs[t] = z[t];
  __syncthreads();
  g_biasall[t] = b1[t];
  if (t < 64) g_biasall[1536 + t] = bc[t];
  for (int l = 0; l < 5; ++l) {
    float accA = ba[l * 256 + t];
    float accB = bb[l * 256 + t];
    const float* rowA = wa + (l * 256 + t) * 256;
    const float* rowB = wb + (l * 256 + t) * 256;
    for (int k = 0; k < 256; k += 4) {
      float4 va = *(const float4*)(rowA + k);
      float4 vb = *(const float4*)(rowB + k);
      accA += va.x * zs[k] + va.y * zs[k + 1] + va.z * zs[k + 2] + va.w * zs[k + 3];
      accB += vb.x * zs[k] + vb.y * zs[k + 1] + vb.z * zs[k + 2] + vb.w * zs[k + 3];
    }
    g_alpha[l * 256 + t] = accA;
    g_biasall[256 + l * 256 + t] = accB;
  }
  for (int j = t; j < 1024; j += 256) {
    float acc = bz[j];
    const float* row = wz + j * 256;
    for (int k = 0; k < 256; k += 4) {
      float4 v = *(const float4*)(row + k);
      acc += v.x * zs[k] + v.y * zs[k + 1] + v.z * zs[k + 2] + v.w * zs[k + 3];
    }
    g_amod[j] = acc;
  }
}

// ---------------- kprep: pack MLP weights into MFMA A-frag layout ----------------
__global__ __launch_bounds__(256) void kprep(
    const float* __restrict__ w1, const float* __restrict__ wma,
    const float* __restrict__ mlw, const float* __restrict__ wc,
    const float* __restrict__ wsig) {
  const int idx = blockIdx.x * 256 + threadIdx.x;
  float val;
  if (idx < 40960) {                      // L1: [w1 | wma | 0], K=160, KSTEPS=5
    int mt = idx / 2560, r2 = idx % 2560;
    int ks = r2 / 512, r = r2 % 512;
    int ln = r >> 3, j = r & 7;
    int oc = mt * 16 + (ln & 15);
    int k = ks * 32 + (ln >> 4) * 8 + j;
    val = (k < 128) ? w1[oc * 128 + k] : ((k < 135) ? wma[oc * 7 + (k - 128)] : 0.f);
  } else if (idx < 368640) {              // ML l: W*alpha, K=256, KSTEPS=8
    int t = idx - 40960;
    int l = t / 65536, t2 = t % 65536;
    int mt = t2 / 4096, r2 = t2 % 4096;
    int ks = r2 / 512, r = r2 % 512;
    int ln = r >> 3, j = r & 7;
    int oc = mt * 16 + (ln & 15);
    int k = ks * 32 + (ln >> 4) * 8 + j;
    val = mlw[l * 65536 + oc * 256 + k] * g_alpha[l * 256 + k];
  } else if (idx < 385024) {              // wc: 64 oc, K=256, KSTEPS=8
    int t = idx - 368640;
    int mt = t / 4096, r2 = t % 4096;
    int ks = r2 / 512, r = r2 % 512;
    int ln = r >> 3, j = r & 7;
    int oc = mt * 16 + (ln & 15);
    int k = ks * 32 + (ln >> 4) * 8 + j;
    val = wc[oc * 256 + k];
  } else {                                // wsig as single-mt frag: row0 = wsig, else 0
    int t = idx - 385024;
    int ks = t / 512, r = t % 512;
    int ln = r >> 3, j = r & 7;
    int row = ln & 15;
    int k = ks * 32 + (ln >> 4) * 8 + j;
    val = (row == 0) ? wsig[k] : 0.f;
  }
  g_wpack[idx] = (short)f2b(val);
}

// ---------------- kprep_cnn ----------------
__global__ __launch_bounds__(256) void kprep_cnn(
    const float* __restrict__ c1w,
    const float* __restrict__ c2aw, const float* __restrict__ c2bw,
    const float* __restrict__ c3aw, const float* __restrict__ c3bw,
    const float* __restrict__ c4aw, const float* __restrict__ c4bw) {
  const int idx = blockIdx.x * 256 + threadIdx.x;
  float val;
  if (idx < 16384) {                       // c1: 256 oc x 64 ic, KS=2
    int mt = idx / 1024, r2 = idx % 1024;
    int ks = r2 / 512, r = r2 % 512;
    int ln = r >> 3, j = r & 7;
    int oc = mt * 16 + (ln & 15);
    int k = ks * 32 + (ln >> 4) * 8 + j;
    val = c1w[oc * 64 + k];
  } else if (idx < O_C4A) {                // 3x3 convs: K = tap*256 + ic, KS=72
    int t = idx - 16384;
    int cv = t / 589824, t2 = t % 589824;
    const float* w = (cv == 0) ? c2aw : (cv == 1) ? c2bw : (cv == 2) ? c3aw : c3bw;
    int mt = t2 / 36864, r2 = t2 % 36864;
    int ks = r2 / 512, r = r2 % 512;
    int ln = r >> 3, j = r & 7;
    int oc = mt * 16 + (ln & 15);
    int k = ks * 32 + (ln >> 4) * 8 + j;
    int tap = k >> 8, ic = k & 255;
    val = w[oc * 2304 + ic * 9 + tap];
  } else {                                 // c4a / c4b: 256x256, KS=8
    int t = idx - O_C4A;
    const float* w = (t < 65536) ? c4aw : c4bw;
    int t2 = t & 65535;
    int mt = t2 / 4096, r2 = t2 % 4096;
    int ks = r2 / 512, r = r2 % 512;
    int ln = r >> 3, j = r & 7;
    int oc = mt * 16 + (ln & 15);
    int k = ks * 32 + (ln >> 4) * 8 + j;
    val = w[oc * 256 + k];
  }
  g_wpack2[idx] = (short)f2b(val);
}

// ---------------- shared helpers ----------------
__device__ __forceinline__ bf16x8 ldsB(const short* buf, int s, int kbyte) {
  const char* p = (const char*)buf + s * 512 + (kbyte ^ ((s & 7) << 4));
  return *(const bf16x8*)p;
}
__device__ __forceinline__ bf16x8 ldA(const short* gA, int frag, int lane) {
  return *(const bf16x8*)(gA + ((size_t)frag << 9) + lane * 8);
}

// ---------------- MFMA MLP: 64 samples / block, 4 waves, IN-PLACE single buffer (R13) ----------------
// bias read directly from g_biasall (L2-hot) -> no LDS staging
template<int KS>
__device__ __forceinline__ void layer_inplace(const short* __restrict__ gA,
    short* __restrict__ fb, const float* __restrict__ bias, int lane, int w) {
  const int lrow = lane & 15;
  const int lkb = (lane >> 4) * 16;
  const int rb = (lane >> 4) * 4;
  f32x4 acc[4][4];
#pragma unroll
  for (int mi = 0; mi < 4; ++mi) {
    const f32x4 bv = *(const f32x4*)(bias + w * 64 + mi * 16 + rb);   // bias in C-in
#pragma unroll
    for (int ni = 0; ni < 4; ++ni) acc[mi][ni] = bv;
  }
#pragma unroll
  for (int ks = 0; ks < KS; ++ks) {
    bf16x8 A[4], B[4];
#pragma unroll
    for (int mi = 0; mi < 4; ++mi)
      A[mi] = ldA(gA, (w * 4 + mi) * KS + ks, lane);
#pragma unroll
    for (int ni = 0; ni < 4; ++ni)
      B[ni] = ldsB(fb, ni * 16 + lrow, ks * 64 + lkb);
#pragma unroll
    for (int mi = 0; mi < 4; ++mi)
#pragma unroll
      for (int ni = 0; ni < 4; ++ni)
        acc[mi][ni] = __builtin_amdgcn_mfma_f32_16x16x32_bf16(A[mi], B[ni], acc[mi][ni], 0, 0, 0);
  }
  __syncthreads();   // all reads of fb complete before any overwrite
#pragma unroll
  for (int mi = 0; mi < 4; ++mi) {
    const int oc0 = w * 64 + mi * 16 + rb;
#pragma unroll
    for (int ni = 0; ni < 4; ++ni) {
      const int s = ni * 16 + lrow;
      f32x4 a = acc[mi][ni];
      char* p = (char*)fb + s * 512 + ((oc0 * 2) ^ ((s & 7) << 4));
      *(int2*)p = make_int2((int)cvtpk(lrelu(a[0]), lrelu(a[1])),
                            (int)cvtpk(lrelu(a[2]), lrelu(a[3])));
    }
  }
  __syncthreads();   // writes visible before next layer reads
}

__global__ __launch_bounds__(256, 2) void kmlp_mfma(
    const float* __restrict__ x, const float* __restrict__ m_in,
    const float* __restrict__ bsig) {
  __shared__ short fbuf[16384];           // [64][256] bf16, swizzled (32 KB), in-place
  const int tid = threadIdx.x;
  const int lane = tid & 63, w = tid >> 6;
  const int s0 = blockIdx.x * 64;

  {  // stage x [64][128] fp32 -> fbuf cols 0..127 (bf16, swizzled)
    const float* xp = x + (size_t)s0 * 128;
    const int s = tid >> 2, c = tid & 3;
#pragma unroll
    for (int e = 0; e < 4; ++e) {
      float4 f0 = *(const float4*)(xp + s * 128 + c * 32 + e * 8);
      float4 f1 = *(const float4*)(xp + s * 128 + c * 32 + e * 8 + 4);
      int4 pk;
      pk.x = (int)cvtpk(f0.x, f0.y); pk.y = (int)cvtpk(f0.z, f0.w);
      pk.z = (int)cvtpk(f1.x, f1.y); pk.w = (int)cvtpk(f1.z, f1.w);
      char* p = (char*)fbuf + s * 512 + ((c * 64 + e * 16) ^ ((s & 7) << 4));
      *(int4*)p = pk;
    }
  }
  if (tid < 64) {  // stage m (7) + zero-pad -> cols 128..159 (L1 reads only K<160)
    const float* mp = m_in + (size_t)(s0 + tid) * 7;
    float mv[8];
#pragma unroll
    for (int q = 0; q < 7; ++q) mv[q] = mp[q];
    mv[7] = 0.f;
    int4 pk;
    pk.x = (int)cvtpk(mv[0], mv[1]); pk.y = (int)cvtpk(mv[2], mv[3]);
    pk.z = (int)cvtpk(mv[4], mv[5]); pk.w = (int)cvtpk(mv[6], mv[7]);
    char* base = (char*)fbuf + tid * 512;
    const int swz = (tid & 7) << 4;
    *(int4*)(base + (256 ^ swz)) = pk;
    int4 zz = make_int4(0, 0, 0, 0);
    *(int4*)(base + (272 ^ swz)) = zz;
    *(int4*)(base + (288 ^ swz)) = zz;
    *(int4*)(base + (304 ^ swz)) = zz;
  }
  __syncthreads();

  const short* gF2 = g_wpack + 40960;
  const short* gF3 = g_wpack + 40960 + 65536;
  const short* gF4 = g_wpack + 40960 + 2 * 65536;
  const short* gF5 = g_wpack + 40960 + 3 * 65536;
  const short* gF6 = g_wpack + 40960 + 4 * 65536;

  layer_inplace<5>(g_wpack, fbuf, g_biasall,        lane, w);   // L1
  layer_inplace<8>(gF2,     fbuf, g_biasall + 256,  lane, w);   // fc_2
  layer_inplace<8>(gF3,     fbuf, g_biasall + 512,  lane, w);   // fc_3
  layer_inplace<8>(gF4,     fbuf, g_biasall + 768,  lane, w);   // fc_4
  {  // sigma via MFMA: wave w covers samples w*16..w*16+15 (reads complete before fc_5 writes)
    const short* gS = g_wpack + 385024;
    const int lrow = lane & 15, lkb = (lane >> 4) * 16;
    f32x4 sacc = {0.f, 0.f, 0.f, 0.f};
#pragma unroll
    for (int ks = 0; ks < 8; ++ks) {
      bf16x8 A = ldA(gS, ks, lane);
      bf16x8 B = ldsB(fbuf, w * 16 + lrow, ks * 64 + lkb);
      sacc = __builtin_amdgcn_mfma_f32_16x16x32_bf16(A, B, sacc, 0, 0, 0);
    }
    if (lane < 16) g_sigma[s0 + w * 16 + lane] = sacc[0] + bsig[0];
  }
  layer_inplace<8>(gF5,     fbuf, g_biasall + 1024, lane, w);   // fc_5
  layer_inplace<8>(gF6,     fbuf, g_biasall + 1280, lane, w);   // fc_6
  {  // c = f@wc^T + bc -> g_c bf16 [sample][64]
    const int lrow = lane & 15, lkb = (lane >> 4) * 16;
    const int rb = (lane >> 4) * 4;
    const int oc0 = w * 16 + rb;
    const f32x4 bv = *(const f32x4*)(g_biasall + 1536 + oc0);
    f32x4 acc[4] = {bv, bv, bv, bv};
    const short* gC = g_wpack + 368640;
#pragma unroll
    for (int ks = 0; ks < 8; ++ks) {
      bf16x8 A = ldA(gC, w * 8 + ks, lane);
#pragma unroll
      for (int ni = 0; ni < 4; ++ni) {
        bf16x8 B = ldsB(fbuf, ni * 16 + lrow, ks * 64 + lkb);
        acc[ni] = __builtin_amdgcn_mfma_f32_16x16x32_bf16(A, B, acc[ni], 0, 0, 0);
      }
    }
#pragma unroll
    for (int ni = 0; ni < 4; ++ni) {
      const int s = ni * 16 + lrow;
      *(int2*)(g_c + (size_t)(s0 + s) * 64 + oc0) =
          make_int2((int)cvtpk(acc[ni][0], acc[ni][1]),
                    (int)cvtpk(acc[ni][2], acc[ni][3]));
    }
  }
}

// ---------------- volumetric compositing -> bf16 feat [px][64] ----------------
__global__ __launch_bounds__(256) void kcomposite(const float* __restrict__ dists) {
  const int tid = threadIdx.x;
  const int p = blockIdx.x * 4 + (tid >> 6);
  const int ch = tid & 63;
  const int base = p * 16;
  float T = 1.f, acc = 0.f;
  for (int mm = 0; mm < 16; ++mm) {
    float sgm = g_sigma[base + mm];
    float d = dists[base + mm];
    float a = 1.f - expf(-fmaxf(sgm, 0.f) * d);
    acc += a * T * b2f(g_c[(size_t)(base + mm) * 64 + ch]);
    T *= (1.f - a + 1e-10f);
  }
  g_featb[p * 64 + ch] = (short)f2b(acc);
}

// ---------------- MFMA 1x1 conv (c1): 32 px x 256 oc / block ----------------
template<int IC>
__global__ __launch_bounds__(256, 2) void kgemm1x1(const short* __restrict__ in,
    const short* __restrict__ gA, const float* __restrict__ bias,
    short* __restrict__ out) {
  constexpr int KS = IC / 32;
  constexpr int ROWB = IC * 2;
  __shared__ short binb[32 * IC];
  const int tid = threadIdx.x;
  const int lane = tid & 63, w = tid >> 6;
  const int px0 = blockIdx.x * 32;

  for (int e = tid; e < 32 * IC / 8; e += 256) {
    const int px = e / (IC / 8), lg = e % (IC / 8);
    bf16x8 v = *(const bf16x8*)(in + (size_t)(px0 + px) * IC + lg * 8);
    char* p = (char*)binb + px * ROWB + ((lg * 16) ^ ((px & 7) << 4));
    *(bf16x8*)p = v;
  }
  __syncthreads();

  const int lrow = lane & 15;
  const int lkb = (lane >> 4) * 16;
  const int rb = (lane >> 4) * 4;
  f32x4 acc[4][2];
#pragma unroll
  for (int mi = 0; mi < 4; ++mi) {
    const f32x4 bv = *(const f32x4*)(bias + w * 64 + mi * 16 + rb);
#pragma unroll
    for (int ni = 0; ni < 2; ++ni) acc[mi][ni] = bv;
  }
#pragma unroll
  for (int ks = 0; ks < KS; ++ks) {
    bf16x8 A[4], B[2];
#pragma unroll
    for (int mi = 0; mi < 4; ++mi)
      A[mi] = ldA(gA, (w * 4 + mi) * KS + ks, lane);
#pragma unroll
    for (int ni = 0; ni < 2; ++ni) {
      const int s = ni * 16 + lrow;
      const char* p = (const char*)binb + s * ROWB + ((ks * 64 + lkb) ^ ((s & 7) << 4));
      B[ni] = *(const bf16x8*)p;
    }
#pragma unroll
    for (int mi = 0; mi < 4; ++mi)
#pragma unroll
      for (int ni = 0; ni < 2; ++ni)
        acc[mi][ni] = __builtin_amdgcn_mfma_f32_16x16x32_bf16(A[mi], B[ni], acc[mi][ni], 0, 0, 0);
  }
#pragma unroll
  for (int mi = 0; mi < 4; ++mi) {
    const int oc = w * 64 + mi * 16 + rb;
#pragma unroll
    for (int ni = 0; ni < 2; ++ni) {
      const int gpx = px0 + ni * 16 + lrow;
      f32x4 a = acc[mi][ni];
      *(int2*)(out + (size_t)gpx * 256 + oc) =
          make_int2((int)cvtpk(lrelu(a[0]), lrelu(a[1])),
                    (int)cvtpk(lrelu(a[2]), lrelu(a[3])));
    }
  }
}

// ---------------- MFMA 3x3 conv: 128 oc x 64 px (2mt x 4ni, R13 form) ----------------
__global__ __launch_bounds__(256, 2) void kconv3(const short* __restrict__ in,
    const short* __restrict__ gA, const float* __restrict__ bias,
    const short* __restrict__ res, int domod, const float* __restrict__ modAB,
    short* __restrict__ out) {
  __shared__ short halo[136 * 256];       // [4x34 spatial][256 ic], 512B rows, swizzled
  const int tid = threadIdx.x;
  const int lane = tid & 63, w = tid >> 6;
  const int oct = blockIdx.x >> 8;
  const int pxt = blockIdx.x & 255;
  const int x0 = (pxt & 3) * 32, y0 = (pxt >> 2) * 2;
  const int oc0 = oct * 128 + w * 32;
  const int lrow = lane & 15;
  const int lkb = (lane >> 4) * 16;
  const int rb = (lane >> 4) * 4;

  for (int e = tid; e < 4352; e += 256) {
    const int row = e >> 5, lg = e & 31;
    const int yy = row / 34, xx = row - yy * 34;
    const int gy = y0 - 1 + yy, gx = x0 - 1 + xx;
    bf16x8 v = {0, 0, 0, 0, 0, 0, 0, 0};
    if (gy >= 0 && gy < 128 && gx >= 0 && gx < 128)
      v = *(const bf16x8*)(in + (size_t)((gy << 7) + gx) * 256 + lg * 8);
    char* p = (char*)halo + row * 512 + ((lg * 16) ^ ((row & 7) << 4));
    *(bf16x8*)p = v;
  }
  __syncthreads();

  const f32x4 zero = {0.f, 0.f, 0.f, 0.f};
  f32x4 acc[2][4];
#pragma unroll
  for (int mi = 0; mi < 2; ++mi) {
    f32x4 bv = zero;
    if (bias) bv = *(const f32x4*)(bias + oc0 + mi * 16 + rb);
#pragma unroll
    for (int ni = 0; ni < 4; ++ni) acc[mi][ni] = bv;
  }

#pragma unroll
  for (int tap = 0; tap < 9; ++tap) {
    const int ky = tap / 3, kx = tap - ky * 3;
#pragma unroll
    for (int s = 0; s < 8; ++s) {
      const int ksg = tap * 8 + s;
      bf16x8 A[2], B[4];
#pragma unroll
      for (int mi = 0; mi < 2; ++mi)
        A[mi] = ldA(gA, (oct * 8 + w * 2 + mi) * 72 + ksg, lane);
#pragma unroll
      for (int ni = 0; ni < 4; ++ni) {
        const int p = ni * 16 + lrow;
        const int row = ((p >> 5) + ky) * 34 + (p & 31) + kx;
        const char* bp = (const char*)halo + row * 512 + ((s * 64 + lkb) ^ ((row & 7) << 4));
        B[ni] = *(const bf16x8*)bp;
      }
#pragma unroll
      for (int mi = 0; mi < 2; ++mi)
#pragma unroll
        for (int ni = 0; ni < 4; ++ni)
          acc[mi][ni] = __builtin_amdgcn_mfma_f32_16x16x32_bf16(A[mi], B[ni], acc[mi][ni], 0, 0, 0);
    }
  }

#pragma unroll
  for (int mi = 0; mi < 2; ++mi) {
    const int oc = oc0 + mi * 16 + rb;
#pragma unroll
    for (int ni = 0; ni < 4; ++ni) {
      const int p = ni * 16 + lrow;
      const int gpx = (y0 + (p >> 5)) * 128 + x0 + (p & 31);
      f32x4 a = acc[mi][ni];
      float v[4] = {a[0], a[1], a[2], a[3]};
      if (res) {
        int2 rv = *(const int2*)(res + (size_t)gpx * 256 + oc);
        v[0] += f_lo(rv.x); v[1] += f_hi(rv.x); v[2] += f_lo(rv.y); v[3] += f_hi(rv.y);
      }
      if (domod) {
#pragma unroll
        for (int r = 0; r < 4; ++r) v[r] = v[r] * (modAB[oc + r] + 1.f) + modAB[256 + oc + r];
      }
      *(int2*)(out + (size_t)gpx * 256 + oc) =
          make_int2((int)cvtpk(lrelu(v[0]), lrelu(v[1])),
                    (int)cvtpk(lrelu(v[2]), lrelu(v[3])));
    }
  }
}

// ---------------- fused c4a -> c4b -> final: 32 px / block ----------------
__device__ __forceinline__ void fuse_gemm(const short* __restrict__ inb,
    const short* __restrict__ gA, const float* __restrict__ bias,
    const short* __restrict__ resb, short* __restrict__ outb, int lane, int w) {
  const int lrow = lane & 15;
  const int lkb = (lane >> 4) * 16;
  const int rb = (lane >> 4) * 4;
  f32x4 acc[4][2];
#pragma unroll
  for (int mi = 0; mi < 4; ++mi) {
    const f32x4 bv = *(const f32x4*)(bias + w * 64 + mi * 16 + rb);
#pragma unroll
    for (int ni = 0; ni < 2; ++ni) acc[mi][ni] = bv;
  }
#pragma unroll
  for (int ks = 0; ks < 8; ++ks) {
    bf16x8 A[4], B[2];
#pragma unroll
    for (int mi = 0; mi < 4; ++mi)
      A[mi] = ldA(gA, (w * 4 + mi) * 8 + ks, lane);
#pragma unroll
    for (int ni = 0; ni < 2; ++ni)
      B[ni] = ldsB(inb, ni * 16 + lrow, ks * 64 + lkb);
#pragma unroll
    for (int mi = 0; mi < 4; ++mi)
#pragma unroll
      for (int ni = 0; ni < 2; ++ni)
        acc[mi][ni] = __builtin_amdgcn_mfma_f32_16x16x32_bf16(A[mi], B[ni], acc[mi][ni], 0, 0, 0);
  }
#pragma unroll
  for (int mi = 0; mi < 4; ++mi) {
    const int oc = w * 64 + mi * 16 + rb;
#pragma unroll
    for (int ni = 0; ni < 2; ++ni) {
      const int s = ni * 16 + lrow;
      f32x4 a = acc[mi][ni];
      float v[4] = {a[0], a[1], a[2], a[3]};
      if (resb) {
        const char* rp = (const char*)resb + s * 512 + ((oc * 2) ^ ((s & 7) << 4));
        int2 rv = *(const int2*)rp;
        v[0] += f_lo(rv.x); v[1] += f_hi(rv.x); v[2] += f_lo(rv.y); v[3] += f_hi(rv.y);
      }
      char* p = (char*)outb + s * 512 + ((oc * 2) ^ ((s & 7) << 4));
      *(int2*)p = make_int2((int)cvtpk(lrelu(v[0]), lrelu(v[1])),
                            (int)cvtpk(lrelu(v[2]), lrelu(v[3])));
    }
  }
}

__global__ __launch_bounds__(256, 2) void kc4fuse(const short* __restrict__ y3,
    const short* __restrict__ gA4a, const short* __restrict__ gA4b,
    const float* __restrict__ c4ab, const float* __restrict__ c4bb,
    const float* __restrict__ c4w, const float* __restrict__ c4b,
    float* __restrict__ outp) {
  __shared__ short binb[32 * 256];   // y3 tile
  __shared__ short tb[32 * 256];     // t tile
  __shared__ short yb[32 * 256];     // y4 tile
  __shared__ float wl[768];
  __shared__ float sred3[768];       // [och][px][g]
  const int tid = threadIdx.x;
  const int lane = tid & 63, w = tid >> 6;
  const int px0 = blockIdx.x * 32;

  for (int e = tid; e < 1024; e += 256) {
    const int px = e >> 5, lg = e & 31;
    bf16x8 v = *(const bf16x8*)(y3 + (size_t)(px0 + px) * 256 + lg * 8);
    char* p = (char*)binb + px * 512 + ((lg * 16) ^ ((px & 7) << 4));
    *(bf16x8*)p = v;
  }
  for (int i = tid; i < 768; i += 256) wl[i] = c4w[i];
  __syncthreads();

  fuse_gemm(binb, gA4a, c4ab, nullptr, tb, lane, w);     // t = lrelu(c4a(y3)+b)
  __syncthreads();
  fuse_gemm(tb, gA4b, c4bb, binb, yb, lane, w);          // y4 = lrelu(y3 + c4b(t) + b)
  __syncthreads();

  {  // final 3-channel 1x1 from LDS
    const int px = tid >> 3, g = tid & 7;
    float s0 = 0.f, s1 = 0.f, s2 = 0.f;
#pragma unroll
    for (int e = 0; e < 4; ++e) {
      bf16x8 v = ldsB(yb, px, g * 64 + e * 16);
      const int ic0 = g * 32 + e * 8;
#pragma unroll
      for (int j = 0; j < 8; ++j) {
        float f = b2f(v[j]);
        s0 += f * wl[ic0 + j];
        s1 += f * wl[256 + ic0 + j];
        s2 += f * wl[512 + ic0 + j];
      }
    }
    sred3[px * 8 + g] = s0;
    sred3[256 + px * 8 + g] = s1;
    sred3[512 + px * 8 + g] = s2;
  }
  __syncthreads();
  if (tid < 96) {
    const int och = tid >> 5, px = tid & 31;
    const float* sp = sred3 + och * 256 + px * 8;
    float s = sp[0] + sp[1] + sp[2] + sp[3] + sp[4] + sp[5] + sp[6] + sp[7];
    outp[och * NPIX + px0 + px] = s + c4b[och];
  }
}

extern "C" void kernel_launch(void* const* d_in, const int* in_sizes, int n_in,
                              void* d_out, int out_size, void* d_ws, size_t ws_size,
                              hipStream_t stream) {
  (void)in_sizes; (void)n_in; (void)out_size; (void)d_ws; (void)ws_size;
  const float* x    = (const float*)d_in[0];
  const float* m    = (const float*)d_in[1];
  const float* z    = (const float*)d_in[2];
  const float* dists= (const float*)d_in[3];
  const float* w1   = (const float*)d_in[4];
  const float* b1   = (const float*)d_in[5];
  const float* wma  = (const float*)d_in[6];
  const float* mlw  = (const float*)d_in[7];
  const float* mlwa = (const float*)d_in[8];
  const float* mlba = (const float*)d_in[9];
  const float* mlwb = (const float*)d_in[10];
  const float* mlbb = (const float*)d_in[11];
  const float* wsig = (const float*)d_in[12];
  const float* bsig = (const float*)d_in[13];
  const float* wc   = (const float*)d_in[14];
  const float* bc   = (const float*)d_in[15];
  const float* wz   = (const float*)d_in[16];
  const float* bz   = (const float*)d_in[17];
  const float* c1w  = (const float*)d_in[18];
  const float* c1b  = (const float*)d_in[19];
  const float* c2aw = (const float*)d_in[20];
  const float* c2ab = (const float*)d_in[21];
  const float* c2bw = (const float*)d_in[22];
  const float* c3aw = (const float*)d_in[23];
  const float* c3ab = (const float*)d_in[24];
  const float* c3bw = (const float*)d_in[25];
  const float* c4aw = (const float*)d_in[26];
  const float* c4ab = (const float*)d_in[27];
  const float* c4bw = (const float*)d_in[28];
  const float* c4bb = (const float*)d_in[29];
  const float* c4w  = (const float*)d_in[30];
  const float* c4b  = (const float*)d_in[31];
  float* outp = (float*)d_out;

  short *pW2, *pFb, *pY1, *pY2, *pY3, *pT;
  float *pAmod;
  hipGetSymbolAddress((void**)&pW2, HIP_SYMBOL(g_wpack2));
  hipGetSymbolAddress((void**)&pFb, HIP_SYMBOL(g_featb));
  hipGetSymbolAddress((void**)&pY1, HIP_SYMBOL(g_y1));
  hipGetSymbolAddress((void**)&pY2, HIP_SYMBOL(g_y2));
  hipGetSymbolAddress((void**)&pY3, HIP_SYMBOL(g_y3));
  hipGetSymbolAddress((void**)&pT,  HIP_SYMBOL(g_t));
  hipGetSymbolAddress((void**)&pAmod, HIP_SYMBOL(g_amod));

  kparams<<<1, 256, 0, stream>>>(z, mlwa, mlba, mlwb, mlbb, wz, bz, b1, bc);
  kprep<<<1520, 256, 0, stream>>>(w1, wma, mlw, wc, wsig);
  kprep_cnn<<<9792, 256, 0, stream>>>(c1w, c2aw, c2bw, c3aw, c3bw, c4aw, c4bw);
  kmlp_mfma<<<4096, 256, 0, stream>>>(x, m, bsig);
  kcomposite<<<4096, 256, 0, stream>>>(dists);
  // RenderCNN (bf16, px-major)
  kgemm1x1<64> <<<512, 256, 0, stream>>>(pFb, pW2 + O_C1, c1b, pY1);                      // y1
  kconv3<<<512, 256, 0, stream>>>(pY1, pW2 + O_C2A, c2ab, nullptr, 0, nullptr,    pT);    // t = lrelu(c2a(y1))
  kconv3<<<512, 256, 0, stream>>>(pT,  pW2 + O_C2B, nullptr, pY1, 1, pAmod,       pY2);   // y2m
  kconv3<<<512, 256, 0, stream>>>(pY2, pW2 + O_C3A, c3ab, nullptr, 0, nullptr,    pT);    // t = lrelu(c3a(y2m))
  kconv3<<<512, 256, 0, stream>>>(pT,  pW2 + O_C3B, nullptr, pY2, 1, pAmod + 512, pY3);   // y3m
  kc4fuse<<<512, 256, 0, stream>>>(pY3, pW2 + O_C4A, pW2 + O_C4B, c4ab, c4bb, c4w, c4b, outp);
}

// Round 17
// 588.462 us; speedup vs baseline: 1.0682x; 1.0682x over previous
//
#include <hip/hip_runtime.h>
#include <hip/hip_bf16.h>

#define NPIX 16384          // 128*128
#define S_TOT 262144        // 128*128*16

typedef __attribute__((ext_vector_type(8))) short bf16x8;
typedef __attribute__((ext_vector_type(4))) float f32x4;

__device__ __forceinline__ float lrelu(float v) { return fmaxf(v, 0.2f * v); }
__device__ __forceinline__ unsigned short f2b(float f) {
  unsigned u = __float_as_uint(f);
  return (unsigned short)((u + 0x7FFFu + ((u >> 16) & 1u)) >> 16);   // RNE
}
// packed f32x2 -> bf16x2 (RNE) [software: HW cvt_pk asm NaN'd, R7]
__device__ __forceinline__ unsigned cvtpk(float a, float b) {
  return (unsigned)f2b(a) | ((unsigned)f2b(b) << 16);
}
__device__ __forceinline__ float b2f(short s) {
  return __uint_as_float(((unsigned)(unsigned short)s) << 16);
}
__device__ __forceinline__ float f_lo(int u) { return __uint_as_float((unsigned)u << 16); }
__device__ __forceinline__ float f_hi(int u) { return __uint_as_float((unsigned)u & 0xffff0000u); }

// ---- device-global scratch (write-before-read each call) ----
__device__ float g_alpha[5 * 256];
__device__ float g_biasall[1600];       // b1(256) | beta l0..4 (1280) | bc(64)
__device__ float g_amod[1024];          // zc = z@wz^T+bz ; a0|a1|a2|a3
__device__ float g_sigma[S_TOT];
__device__ short g_c[S_TOT * 64];       // bf16 [sample][64]
__device__ short g_featb[NPIX * 64];    // bf16 [px][64]
__device__ short g_y1[NPIX * 256];      // bf16 [px][256]
__device__ short g_y2[NPIX * 256];
__device__ short g_y3[NPIX * 256];
__device__ short g_t [NPIX * 256];
// MLP packed A-frags: L1 (K=160) 40960 | 5x ML (K=256) 65536 ea | wc 16384 | wsig 4096
__device__ short g_wpack[389120];
// CNN packed A-frags: c1(16384) | c2a,c2b,c3a,c3b (589824 ea) | c4a,c4b (65536 ea)
#define O_C1  0
#define O_C2A 16384
#define O_C2B (16384 + 589824)
#define O_C3A (16384 + 2 * 589824)
#define O_C3B (16384 + 3 * 589824)
#define O_C4A (16384 + 4 * 589824)
#define O_C4B (16384 + 4 * 589824 + 65536)
__device__ short g_wpack2[2506752];

// ---------------- kparams ----------------
__global__ __launch_bounds__(256) void kparams(const float* __restrict__ z,
    const float* __restrict__ wa, const float* __restrict__ ba,
    const float* __restrict__ wb, const float* __restrict__ bb,
    const float* __restrict__ wz, const float* __restrict__ bz,
    const float* __restrict__ b1, const float* __restrict__ bc) {
  __shared__ float zs[256];
  const int t = threadIdx.x;
  zs[t] = z[t];
  __syncthreads();
  g_biasall[t] = b1[t];
  if (t < 64) g_biasall[1536 + t] = bc[t];
  for (int l = 0; l < 5; ++l) {
    float accA = ba[l * 256 + t];
    float accB = bb[l * 256 + t];
    const float* rowA = wa + (l * 256 + t) * 256;
    const float* rowB = wb + (l * 256 + t) * 256;
    for (int k = 0; k < 256; k += 4) {
      float4 va = *(const float4*)(rowA + k);
      float4 vb = *(const float4*)(rowB + k);
      accA += va.x * zs[k] + va.y * zs[k + 1] + va.z * zs[k + 2] + va.w * zs[k + 3];
      accB += vb.x * zs[k] + vb.y * zs[k + 1] + vb.z * zs[k + 2] + vb.w * zs[k + 3];
    }
    g_alpha[l * 256 + t] = accA;
    g_biasall[256 + l * 256 + t] = accB;
  }
  for (int j = t; j < 1024; j += 256) {
    float acc = bz[j];
    const float* row = wz + j * 256;
    for (int k = 0; k < 256; k += 4) {
      float4 v = *(const float4*)(row + k);
      acc += v.x * zs[k] + v.y * zs[k + 1] + v.z * zs[k + 2] + v.w * zs[k + 3];
    }
    g_amod[j] = acc;
  }
}

// ---------------- kprep: pack MLP weights into MFMA A-frag layout ----------------
__global__ __launch_bounds__(256) void kprep(
    const float* __restrict__ w1, const float* __restrict__ wma,
    const float* __restrict__ mlw, const float* __restrict__ wc,
    const float* __restrict__ wsig) {
  const int idx = blockIdx.x * 256 + threadIdx.x;
  float val;
  if (idx < 40960) {                      // L1: [w1 | wma | 0], K=160, KSTEPS=5
    int mt = idx / 2560, r2 = idx % 2560;
    int ks = r2 / 512, r = r2 % 512;
    int ln = r >> 3, j = r & 7;
    int oc = mt * 16 + (ln & 15);
    int k = ks * 32 + (ln >> 4) * 8 + j;
    val = (k < 128) ? w1[oc * 128 + k] : ((k < 135) ? wma[oc * 7 + (k - 128)] : 0.f);
  } else if (idx < 368640) {              // ML l: W*alpha, K=256, KSTEPS=8
    int t = idx - 40960;
    int l = t / 65536, t2 = t % 65536;
    int mt = t2 / 4096, r2 = t2 % 4096;
    int ks = r2 / 512, r = r2 % 512;
    int ln = r >> 3, j = r & 7;
    int oc = mt * 16 + (ln & 15);
    int k = ks * 32 + (ln >> 4) * 8 + j;
    val = mlw[l * 65536 + oc * 256 + k] * g_alpha[l * 256 + k];
  } else if (idx < 385024) {              // wc: 64 oc, K=256, KSTEPS=8
    int t = idx - 368640;
    int mt = t / 4096, r2 = t % 4096;
    int ks = r2 / 512, r = r2 % 512;
    int ln = r >> 3, j = r & 7;
    int oc = mt * 16 + (ln & 15);
    int k = ks * 32 + (ln >> 4) * 8 + j;
    val = wc[oc * 256 + k];
  } else {                                // wsig as single-mt frag: row0 = wsig, else 0
    int t = idx - 385024;
    int ks = t / 512, r = t % 512;
    int ln = r >> 3, j = r & 7;
    int row = ln & 15;
    int k = ks * 32 + (ln >> 4) * 8 + j;
    val = (row == 0) ? wsig[k] : 0.f;
  }
  g_wpack[idx] = (short)f2b(val);
}

// ---------------- kprep_cnn ----------------
__global__ __launch_bounds__(256) void kprep_cnn(
    const float* __restrict__ c1w,
    const float* __restrict__ c2aw, const float* __restrict__ c2bw,
    const float* __restrict__ c3aw, const float* __restrict__ c3bw,
    const float* __restrict__ c4aw, const float* __restrict__ c4bw) {
  const int idx = blockIdx.x * 256 + threadIdx.x;
  float val;
  if (idx < 16384) {                       // c1: 256 oc x 64 ic, KS=2
    int mt = idx / 1024, r2 = idx % 1024;
    int ks = r2 / 512, r = r2 % 512;
    int ln = r >> 3, j = r & 7;
    int oc = mt * 16 + (ln & 15);
    int k = ks * 32 + (ln >> 4) * 8 + j;
    val = c1w[oc * 64 + k];
  } else if (idx < O_C4A) {                // 3x3 convs: K = tap*256 + ic, KS=72
    int t = idx - 16384;
    int cv = t / 589824, t2 = t % 589824;
    const float* w = (cv == 0) ? c2aw : (cv == 1) ? c2bw : (cv == 2) ? c3aw : c3bw;
    int mt = t2 / 36864, r2 = t2 % 36864;
    int ks = r2 / 512, r = r2 % 512;
    int ln = r >> 3, j = r & 7;
    int oc = mt * 16 + (ln & 15);
    int k = ks * 32 + (ln >> 4) * 8 + j;
    int tap = k >> 8, ic = k & 255;
    val = w[oc * 2304 + ic * 9 + tap];
  } else {                                 // c4a / c4b: 256x256, KS=8
    int t = idx - O_C4A;
    const float* w = (t < 65536) ? c4aw : c4bw;
    int t2 = t & 65535;
    int mt = t2 / 4096, r2 = t2 % 4096;
    int ks = r2 / 512, r = r2 % 512;
    int ln = r >> 3, j = r & 7;
    int oc = mt * 16 + (ln & 15);
    int k = ks * 32 + (ln >> 4) * 8 + j;
    val = w[oc * 256 + k];
  }
  g_wpack2[idx] = (short)f2b(val);
}

// ---------------- shared helpers ----------------
__device__ __forceinline__ bf16x8 ldsB(const short* buf, int s, int kbyte) {
  const char* p = (const char*)buf + s * 512 + (kbyte ^ ((s & 7) << 4));
  return *(const bf16x8*)p;
}
__device__ __forceinline__ bf16x8 ldA(const short* gA, int frag, int lane) {
  return *(const bf16x8*)(gA + ((size_t)frag << 9) + lane * 8);
}

// ---------------- MFMA MLP: 64 samples / block, 4 waves, IN-PLACE single buffer ----------------
// wave w owns oc [w*64, w*64+64). Read phase (all K) -> bar -> write own columns -> bar.
template<int KS>
__device__ __forceinline__ void layer_inplace(const short* __restrict__ gA,
    short* __restrict__ fb, const float* __restrict__ bias, int lane, int w) {
  const int lrow = lane & 15;
  const int lkb = (lane >> 4) * 16;
  const int rb = (lane >> 4) * 4;
  f32x4 acc[4][4];
#pragma unroll
  for (int mi = 0; mi < 4; ++mi) {
    const f32x4 bv = *(const f32x4*)(bias + w * 64 + mi * 16 + rb);   // bias in C-in
#pragma unroll
    for (int ni = 0; ni < 4; ++ni) acc[mi][ni] = bv;
  }
#pragma unroll
  for (int ks = 0; ks < KS; ++ks) {
    bf16x8 A[4], B[4];
#pragma unroll
    for (int mi = 0; mi < 4; ++mi)
      A[mi] = ldA(gA, (w * 4 + mi) * KS + ks, lane);
#pragma unroll
    for (int ni = 0; ni < 4; ++ni)
      B[ni] = ldsB(fb, ni * 16 + lrow, ks * 64 + lkb);
#pragma unroll
    for (int mi = 0; mi < 4; ++mi)
#pragma unroll
      for (int ni = 0; ni < 4; ++ni)
        acc[mi][ni] = __builtin_amdgcn_mfma_f32_16x16x32_bf16(A[mi], B[ni], acc[mi][ni], 0, 0, 0);
  }
  __syncthreads();   // all reads of fb complete before any overwrite
#pragma unroll
  for (int mi = 0; mi < 4; ++mi) {
    const int oc0 = w * 64 + mi * 16 + rb;
#pragma unroll
    for (int ni = 0; ni < 4; ++ni) {
      const int s = ni * 16 + lrow;
      f32x4 a = acc[mi][ni];
      char* p = (char*)fb + s * 512 + ((oc0 * 2) ^ ((s & 7) << 4));
      *(int2*)p = make_int2((int)cvtpk(lrelu(a[0]), lrelu(a[1])),
                            (int)cvtpk(lrelu(a[2]), lrelu(a[3])));
    }
  }
  __syncthreads();   // writes visible before next layer reads
}

__global__ __launch_bounds__(256, 2) void kmlp_mfma(
    const float* __restrict__ x, const float* __restrict__ m_in,
    const float* __restrict__ bsig) {
  __shared__ short fbuf[16384];           // [64][256] bf16, swizzled (32 KB), in-place
  __shared__ float bias_all[1600];
  const int tid = threadIdx.x;
  const int lane = tid & 63, w = tid >> 6;
  const int s0 = blockIdx.x * 64;

  {  // stage x [64][128] fp32 -> fbuf cols 0..127 (bf16, swizzled)
    const float* xp = x + (size_t)s0 * 128;
    const int s = tid >> 2, c = tid & 3;
#pragma unroll
    for (int e = 0; e < 4; ++e) {
      float4 f0 = *(const float4*)(xp + s * 128 + c * 32 + e * 8);
      float4 f1 = *(const float4*)(xp + s * 128 + c * 32 + e * 8 + 4);
      int4 pk;
      pk.x = (int)cvtpk(f0.x, f0.y); pk.y = (int)cvtpk(f0.z, f0.w);
      pk.z = (int)cvtpk(f1.x, f1.y); pk.w = (int)cvtpk(f1.z, f1.w);
      char* p = (char*)fbuf + s * 512 + ((c * 64 + e * 16) ^ ((s & 7) << 4));
      *(int4*)p = pk;
    }
  }
  if (tid < 64) {  // stage m (7) + zero-pad -> cols 128..159 (L1 reads only K<160)
    const float* mp = m_in + (size_t)(s0 + tid) * 7;
    float mv[8];
#pragma unroll
    for (int q = 0; q < 7; ++q) mv[q] = mp[q];
    mv[7] = 0.f;
    int4 pk;
    pk.x = (int)cvtpk(mv[0], mv[1]); pk.y = (int)cvtpk(mv[2], mv[3]);
    pk.z = (int)cvtpk(mv[4], mv[5]); pk.w = (int)cvtpk(mv[6], mv[7]);
    char* base = (char*)fbuf + tid * 512;
    const int swz = (tid & 7) << 4;
    *(int4*)(base + (256 ^ swz)) = pk;
    int4 zz = make_int4(0, 0, 0, 0);
    *(int4*)(base + (272 ^ swz)) = zz;
    *(int4*)(base + (288 ^ swz)) = zz;
    *(int4*)(base + (304 ^ swz)) = zz;
  }
  for (int i = tid; i < 1600; i += 256) bias_all[i] = g_biasall[i];
  __syncthreads();

  const short* gF2 = g_wpack + 40960;
  const short* gF3 = g_wpack + 40960 + 65536;
  const short* gF4 = g_wpack + 40960 + 2 * 65536;
  const short* gF5 = g_wpack + 40960 + 3 * 65536;
  const short* gF6 = g_wpack + 40960 + 4 * 65536;

  layer_inplace<5>(g_wpack, fbuf, bias_all,        lane, w);   // L1
  layer_inplace<8>(gF2,     fbuf, bias_all + 256,  lane, w);   // fc_2
  layer_inplace<8>(gF3,     fbuf, bias_all + 512,  lane, w);   // fc_3
  layer_inplace<8>(gF4,     fbuf, bias_all + 768,  lane, w);   // fc_4
  {  // sigma via MFMA: wave w covers samples w*16..w*16+15 (reads complete before fc_5 writes)
    const short* gS = g_wpack + 385024;
    const int lrow = lane & 15, lkb = (lane >> 4) * 16;
    f32x4 sacc = {0.f, 0.f, 0.f, 0.f};
#pragma unroll
    for (int ks = 0; ks < 8; ++ks) {
      bf16x8 A = ldA(gS, ks, lane);
      bf16x8 B = ldsB(fbuf, w * 16 + lrow, ks * 64 + lkb);
      sacc = __builtin_amdgcn_mfma_f32_16x16x32_bf16(A, B, sacc, 0, 0, 0);
    }
    if (lane < 16) g_sigma[s0 + w * 16 + lane] = sacc[0] + bsig[0];
  }
  layer_inplace<8>(gF5,     fbuf, bias_all + 1024, lane, w);   // fc_5
  layer_inplace<8>(gF6,     fbuf, bias_all + 1280, lane, w);   // fc_6
  {  // c = f@wc^T + bc -> g_c bf16 [sample][64]
    const int lrow = lane & 15, lkb = (lane >> 4) * 16;
    const int rb = (lane >> 4) * 4;
    const int oc0 = w * 16 + rb;
    const f32x4 bv = *(const f32x4*)(bias_all + 1536 + oc0);
    f32x4 acc[4] = {bv, bv, bv, bv};
    const short* gC = g_wpack + 368640;
#pragma unroll
    for (int ks = 0; ks < 8; ++ks) {
      bf16x8 A = ldA(gC, w * 8 + ks, lane);
#pragma unroll
      for (int ni = 0; ni < 4; ++ni) {
        bf16x8 B = ldsB(fbuf, ni * 16 + lrow, ks * 64 + lkb);
        acc[ni] = __builtin_amdgcn_mfma_f32_16x16x32_bf16(A, B, acc[ni], 0, 0, 0);
      }
    }
#pragma unroll
    for (int ni = 0; ni < 4; ++ni) {
      const int s = ni * 16 + lrow;
      *(int2*)(g_c + (size_t)(s0 + s) * 64 + oc0) =
          make_int2((int)cvtpk(acc[ni][0], acc[ni][1]),
                    (int)cvtpk(acc[ni][2], acc[ni][3]));
    }
  }
}

// ---------------- volumetric compositing -> bf16 feat [px][64] ----------------
__global__ __launch_bounds__(256) void kcomposite(const float* __restrict__ dists) {
  const int tid = threadIdx.x;
  const int p = blockIdx.x * 4 + (tid >> 6);
  const int ch = tid & 63;
  const int base = p * 16;
  float T = 1.f, acc = 0.f;
  for (int mm = 0; mm < 16; ++mm) {
    float sgm = g_sigma[base + mm];
    float d = dists[base + mm];
    float a = 1.f - expf(-fmaxf(sgm, 0.f) * d);
    acc += a * T * b2f(g_c[(size_t)(base + mm) * 64 + ch]);
    T *= (1.f - a + 1e-10f);
  }
  g_featb[p * 64 + ch] = (short)f2b(acc);
}

// ---------------- MFMA 1x1 conv (c1): 32 px x 256 oc / block ----------------
template<int IC>
__global__ __launch_bounds__(256, 2) void kgemm1x1(const short* __restrict__ in,
    const short* __restrict__ gA, const float* __restrict__ bias,
    short* __restrict__ out) {
  constexpr int KS = IC / 32;
  constexpr int ROWB = IC * 2;
  __shared__ short binb[32 * IC];
  const int tid = threadIdx.x;
  const int lane = tid & 63, w = tid >> 6;
  const int px0 = blockIdx.x * 32;

  for (int e = tid; e < 32 * IC / 8; e += 256) {
    const int px = e / (IC / 8), lg = e % (IC / 8);
    bf16x8 v = *(const bf16x8*)(in + (size_t)(px0 + px) * IC + lg * 8);
    char* p = (char*)binb + px * ROWB + ((lg * 16) ^ ((px & 7) << 4));
    *(bf16x8*)p = v;
  }
  __syncthreads();

  const int lrow = lane & 15;
  const int lkb = (lane >> 4) * 16;
  const int rb = (lane >> 4) * 4;
  f32x4 acc[4][2];
#pragma unroll
  for (int mi = 0; mi < 4; ++mi) {
    const f32x4 bv = *(const f32x4*)(bias + w * 64 + mi * 16 + rb);
#pragma unroll
    for (int ni = 0; ni < 2; ++ni) acc[mi][ni] = bv;
  }
#pragma unroll
  for (int ks = 0; ks < KS; ++ks) {
    bf16x8 A[4], B[2];
#pragma unroll
    for (int mi = 0; mi < 4; ++mi)
      A[mi] = ldA(gA, (w * 4 + mi) * KS + ks, lane);
#pragma unroll
    for (int ni = 0; ni < 2; ++ni) {
      const int s = ni * 16 + lrow;
      const char* p = (const char*)binb + s * ROWB + ((ks * 64 + lkb) ^ ((s & 7) << 4));
      B[ni] = *(const bf16x8*)p;
    }
#pragma unroll
    for (int mi = 0; mi < 4; ++mi)
#pragma unroll
      for (int ni = 0; ni < 2; ++ni)
        acc[mi][ni] = __builtin_amdgcn_mfma_f32_16x16x32_bf16(A[mi], B[ni], acc[mi][ni], 0, 0, 0);
  }
#pragma unroll
  for (int mi = 0; mi < 4; ++mi) {
    const int oc = w * 64 + mi * 16 + rb;
#pragma unroll
    for (int ni = 0; ni < 2; ++ni) {
      const int gpx = px0 + ni * 16 + lrow;
      f32x4 a = acc[mi][ni];
      *(int2*)(out + (size_t)gpx * 256 + oc) =
          make_int2((int)cvtpk(lrelu(a[0]), lrelu(a[1])),
                    (int)cvtpk(lrelu(a[2]), lrelu(a[3])));
    }
  }
}

// ---------------- MFMA 3x3 conv: 128 oc x 64 px, full-depth halo staged once ----------------
__global__ __launch_bounds__(256, 2) void kconv3(const short* __restrict__ in,
    const short* __restrict__ gA, const float* __restrict__ bias,
    const short* __restrict__ res, int domod, const float* __restrict__ modAB,
    short* __restrict__ out) {
  __shared__ short halo[136 * 256];       // [4x34 spatial][256 ic], 512B rows, swizzled
  const int tid = threadIdx.x;
  const int lane = tid & 63, w = tid >> 6;
  const int oct = blockIdx.x >> 8;
  const int pxt = blockIdx.x & 255;
  const int x0 = (pxt & 3) * 32, y0 = (pxt >> 2) * 2;
  const int oc0 = oct * 128 + w * 32;
  const int lrow = lane & 15;
  const int lkb = (lane >> 4) * 16;
  const int rb = (lane >> 4) * 4;

  for (int e = tid; e < 4352; e += 256) {
    const int row = e >> 5, lg = e & 31;
    const int yy = row / 34, xx = row - yy * 34;
    const int gy = y0 - 1 + yy, gx = x0 - 1 + xx;
    bf16x8 v = {0, 0, 0, 0, 0, 0, 0, 0};
    if (gy >= 0 && gy < 128 && gx >= 0 && gx < 128)
      v = *(const bf16x8*)(in + (size_t)((gy << 7) + gx) * 256 + lg * 8);
    char* p = (char*)halo + row * 512 + ((lg * 16) ^ ((row & 7) << 4));
    *(bf16x8*)p = v;
  }
  __syncthreads();

  const f32x4 zero = {0.f, 0.f, 0.f, 0.f};
  f32x4 acc[2][4];
#pragma unroll
  for (int mi = 0; mi < 2; ++mi) {
    f32x4 bv = zero;
    if (bias) bv = *(const f32x4*)(bias + oc0 + mi * 16 + rb);
#pragma unroll
    for (int ni = 0; ni < 4; ++ni) acc[mi][ni] = bv;
  }

#pragma unroll
  for (int tap = 0; tap < 9; ++tap) {
    const int ky = tap / 3, kx = tap - ky * 3;
#pragma unroll
    for (int s = 0; s < 8; ++s) {
      const int ksg = tap * 8 + s;
      bf16x8 A[2], B[4];
#pragma unroll
      for (int mi = 0; mi < 2; ++mi)
        A[mi] = ldA(gA, (oct * 8 + w * 2 + mi) * 72 + ksg, lane);
#pragma unroll
      for (int ni = 0; ni < 4; ++ni) {
        const int p = ni * 16 + lrow;
        const int row = ((p >> 5) + ky) * 34 + (p & 31) + kx;
        const char* bp = (const char*)halo + row * 512 + ((s * 64 + lkb) ^ ((row & 7) << 4));
        B[ni] = *(const bf16x8*)bp;
      }
#pragma unroll
      for (int mi = 0; mi < 2; ++mi)
#pragma unroll
        for (int ni = 0; ni < 4; ++ni)
          acc[mi][ni] = __builtin_amdgcn_mfma_f32_16x16x32_bf16(A[mi], B[ni], acc[mi][ni], 0, 0, 0);
    }
  }

#pragma unroll
  for (int mi = 0; mi < 2; ++mi) {
    const int oc = oc0 + mi * 16 + rb;
#pragma unroll
    for (int ni = 0; ni < 4; ++ni) {
      const int p = ni * 16 + lrow;
      const int gpx = (y0 + (p >> 5)) * 128 + x0 + (p & 31);
      f32x4 a = acc[mi][ni];
      float v[4] = {a[0], a[1], a[2], a[3]};
      if (res) {
        int2 rv = *(const int2*)(res + (size_t)gpx * 256 + oc);
        v[0] += f_lo(rv.x); v[1] += f_hi(rv.x); v[2] += f_lo(rv.y); v[3] += f_hi(rv.y);
      }
      if (domod) {
#pragma unroll
        for (int r = 0; r < 4; ++r) v[r] = v[r] * (modAB[oc + r] + 1.f) + modAB[256 + oc + r];
      }
      *(int2*)(out + (size_t)gpx * 256 + oc) =
          make_int2((int)cvtpk(lrelu(v[0]), lrelu(v[1])),
                    (int)cvtpk(lrelu(v[2]), lrelu(v[3])));
    }
  }
}

// ---------------- fused c4a -> c4b -> final: 32 px / block ----------------
__device__ __forceinline__ void fuse_gemm(const short* __restrict__ inb,
    const short* __restrict__ gA, const float* __restrict__ bias,
    const short* __restrict__ resb, short* __restrict__ outb, int lane, int w) {
  const int lrow = lane & 15;
  const int lkb = (lane >> 4) * 16;
  const int rb = (lane >> 4) * 4;
  f32x4 acc[4][2];
#pragma unroll
  for (int mi = 0; mi < 4; ++mi) {
    const f32x4 bv = *(const f32x4*)(bias + w * 64 + mi * 16 + rb);
#pragma unroll
    for (int ni = 0; ni < 2; ++ni) acc[mi][ni] = bv;
  }
#pragma unroll
  for (int ks = 0; ks < 8; ++ks) {
    bf16x8 A[4], B[2];
#pragma unroll
    for (int mi = 0; mi < 4; ++mi)
      A[mi] = ldA(gA, (w * 4 + mi) * 8 + ks, lane);
#pragma unroll
    for (int ni = 0; ni < 2; ++ni)
      B[ni] = ldsB(inb, ni * 16 + lrow, ks * 64 + lkb);
#pragma unroll
    for (int mi = 0; mi < 4; ++mi)
#pragma unroll
      for (int ni = 0; ni < 2; ++ni)
        acc[mi][ni] = __builtin_amdgcn_mfma_f32_16x16x32_bf16(A[mi], B[ni], acc[mi][ni], 0, 0, 0);
  }
#pragma unroll
  for (int mi = 0; mi < 4; ++mi) {
    const int oc = w * 64 + mi * 16 + rb;
#pragma unroll
    for (int ni = 0; ni < 2; ++ni) {
      const int s = ni * 16 + lrow;
      f32x4 a = acc[mi][ni];
      float v[4] = {a[0], a[1], a[2], a[3]};
      if (resb) {
        const char* rp = (const char*)resb + s * 512 + ((oc * 2) ^ ((s & 7) << 4));
        int2 rv = *(const int2*)rp;
        v[0] += f_lo(rv.x); v[1] += f_hi(rv.x); v[2] += f_lo(rv.y); v[3] += f_hi(rv.y);
      }
      char* p = (char*)outb + s * 512 + ((oc * 2) ^ ((s & 7) << 4));
      *(int2*)p = make_int2((int)cvtpk(lrelu(v[0]), lrelu(v[1])),
                            (int)cvtpk(lrelu(v[2]), lrelu(v[3])));
    }
  }
}

__global__ __launch_bounds__(256, 2) void kc4fuse(const short* __restrict__ y3,
    const short* __restrict__ gA4a, const short* __restrict__ gA4b,
    const float* __restrict__ c4ab, const float* __restrict__ c4bb,
    const float* __restrict__ c4w, const float* __restrict__ c4b,
    float* __restrict__ outp) {
  __shared__ short binb[32 * 256];   // y3 tile
  __shared__ short tb[32 * 256];     // t tile
  __shared__ short yb[32 * 256];     // y4 tile
  __shared__ float wl[768];
  __shared__ float sred3[768];       // [och][px][g]
  const int tid = threadIdx.x;
  const int lane = tid & 63, w = tid >> 6;
  const int px0 = blockIdx.x * 32;

  for (int e = tid; e < 1024; e += 256) {
    const int px = e >> 5, lg = e & 31;
    bf16x8 v = *(const bf16x8*)(y3 + (size_t)(px0 + px) * 256 + lg * 8);
    char* p = (char*)binb + px * 512 + ((lg * 16) ^ ((px & 7) << 4));
    *(bf16x8*)p = v;
  }
  for (int i = tid; i < 768; i += 256) wl[i] = c4w[i];
  __syncthreads();

  fuse_gemm(binb, gA4a, c4ab, nullptr, tb, lane, w);     // t = lrelu(c4a(y3)+b)
  __syncthreads();
  fuse_gemm(tb, gA4b, c4bb, binb, yb, lane, w);          // y4 = lrelu(y3 + c4b(t) + b)
  __syncthreads();

  {  // final 3-channel 1x1 from LDS
    const int px = tid >> 3, g = tid & 7;
    float s0 = 0.f, s1 = 0.f, s2 = 0.f;
#pragma unroll
    for (int e = 0; e < 4; ++e) {
      bf16x8 v = ldsB(yb, px, g * 64 + e * 16);
      const int ic0 = g * 32 + e * 8;
#pragma unroll
      for (int j = 0; j < 8; ++j) {
        float f = b2f(v[j]);
        s0 += f * wl[ic0 + j];
        s1 += f * wl[256 + ic0 + j];
        s2 += f * wl[512 + ic0 + j];
      }
    }
    sred3[px * 8 + g] = s0;
    sred3[256 + px * 8 + g] = s1;
    sred3[512 + px * 8 + g] = s2;
  }
  __syncthreads();
  if (tid < 96) {
    const int och = tid >> 5, px = tid & 31;
    const float* sp = sred3 + och * 256 + px * 8;
    float s = sp[0] + sp[1] + sp[2] + sp[3] + sp[4] + sp[5] + sp[6] + sp[7];
    outp[och * NPIX + px0 + px] = s + c4b[och];
  }
}

extern "C" void kernel_launch(void* const* d_in, const int* in_sizes, int n_in,
                              void* d_out, int out_size, void* d_ws, size_t ws_size,
                              hipStream_t stream) {
  (void)in_sizes; (void)n_in; (void)out_size; (void)d_ws; (void)ws_size;
  const float* x    = (const float*)d_in[0];
  const float* m    = (const float*)d_in[1];
  const float* z    = (const float*)d_in[2];
  const float* dists= (const float*)d_in[3];
  const float* w1   = (const float*)d_in[4];
  const float* b1   = (const float*)d_in[5];
  const float* wma  = (const float*)d_in[6];
  const float* mlw  = (const float*)d_in[7];
  const float* mlwa = (const float*)d_in[8];
  const float* mlba = (const float*)d_in[9];
  const float* mlwb = (const float*)d_in[10];
  const float* mlbb = (const float*)d_in[11];
  const float* wsig = (const float*)d_in[12];
  const float* bsig = (const float*)d_in[13];
  const float* wc   = (const float*)d_in[14];
  const float* bc   = (const float*)d_in[15];
  const float* wz   = (const float*)d_in[16];
  const float* bz   = (const float*)d_in[17];
  const float* c1w  = (const float*)d_in[18];
  const float* c1b  = (const float*)d_in[19];
  const float* c2aw = (const float*)d_in[20];
  const float* c2ab = (const float*)d_in[21];
  const float* c2bw = (const float*)d_in[22];
  const float* c3aw = (const float*)d_in[23];
  const float* c3ab = (const float*)d_in[24];
  const float* c3bw = (const float*)d_in[25];
  const float* c4aw = (const float*)d_in[26];
  const float* c4ab = (const float*)d_in[27];
  const float* c4bw = (const float*)d_in[28];
  const float* c4bb = (const float*)d_in[29];
  const float* c4w  = (const float*)d_in[30];
  const float* c4b  = (const float*)d_in[31];
  float* outp = (float*)d_out;

  short *pW2, *pFb, *pY1, *pY2, *pY3, *pT;
  float *pAmod;
  hipGetSymbolAddress((void**)&pW2, HIP_SYMBOL(g_wpack2));
  hipGetSymbolAddress((void**)&pFb, HIP_SYMBOL(g_featb));
  hipGetSymbolAddress((void**)&pY1, HIP_SYMBOL(g_y1));
  hipGetSymbolAddress((void**)&pY2, HIP_SYMBOL(g_y2));
  hipGetSymbolAddress((void**)&pY3, HIP_SYMBOL(g_y3));
  hipGetSymbolAddress((void**)&pT,  HIP_SYMBOL(g_t));
  hipGetSymbolAddress((void**)&pAmod, HIP_SYMBOL(g_amod));

  kparams<<<1, 256, 0, stream>>>(z, mlwa, mlba, mlwb, mlbb, wz, bz, b1, bc);
  kprep<<<1520, 256, 0, stream>>>(w1, wma, mlw, wc, wsig);
  kprep_cnn<<<9792, 256, 0, stream>>>(c1w, c2aw, c2bw, c3aw, c3bw, c4aw, c4bw);
  kmlp_mfma<<<4096, 256, 0, stream>>>(x, m, bsig);
  kcomposite<<<4096, 256, 0, stream>>>(dists);
  // RenderCNN (bf16, px-major)
  kgemm1x1<64> <<<512, 256, 0, stream>>>(pFb, pW2 + O_C1, c1b, pY1);                      // y1
  kconv3<<<512, 256, 0, stream>>>(pY1, pW2 + O_C2A, c2ab, nullptr, 0, nullptr,    pT);    // t = lrelu(c2a(y1))
  kconv3<<<512, 256, 0, stream>>>(pT,  pW2 + O_C2B, nullptr, pY1, 1, pAmod,       pY2);   // y2m
  kconv3<<<512, 256, 0, stream>>>(pY2, pW2 + O_C3A, c3ab, nullptr, 0, nullptr,    pT);    // t = lrelu(c3a(y2m))
  kconv3<<<512, 256, 0, stream>>>(pT,  pW2 + O_C3B, nullptr, pY2, 1, pAmod + 512, pY3);   // y3m
  kc4fuse<<<512, 256, 0, stream>>>(pY3, pW2 + O_C4A, pW2 + O_C4B, c4ab, c4bb, c4w, c4b, outp);
}